// Round 10
// baseline (627.433 us; speedup 1.0000x reference)
//
#include <hip/hip_runtime.h>

// GNN: 3x (GCNConv -> BN -> ReLU) -> mean/max pool per graph -> 3-layer MLP.
// N=50000 nodes, E=800000 edges, F=H=128, G=1024 graphs.
// conv bias cancels inside BatchNorm (mean-subtraction) -> skipped entirely.
// CSR build: block-level LDS histogram + one line-padded global cursor
// reservation per (block,bucket) -> dense packed-4B tmp scatter -> per-bucket
// LDS fine sort. No deep same-line atomic serialization anywhere.
// H2 and B activations stored bf16 (BN is self-consistent on bf16 values).
// GEMM: MFMA 16x16x32 bf16, no LDS; W pre-packed into fragment order.
// Aggregation fuses BN-stats accumulation (values already in registers).
// BN-apply+ReLU folded into the NEXT consumer (GEMM staging / pooling).
// Pooling uses sorted `batch` (binary-searched boundaries) -> no atomics.

constexpr int FH = 128;     // feature dim
constexpr int GG = 1024;    // graphs
constexpr int NAB = 512;    // aggregate blocks = stats partial blocks
constexpr int BKS = 1024;   // max 64-node buckets in LDS (n <= 65536; also needed for 16b src pack)
constexpr int CPAD = 16;    // global cursor padding in ints = one 64B line
constexpr int EPB = 4096;   // edges per partition block
constexpr float EPSV = 1e-5f;

typedef __attribute__((ext_vector_type(8))) short short8v;   // 8 bf16 (4 VGPRs)
typedef __attribute__((ext_vector_type(4))) float f32x4;     // MFMA acc

__device__ inline unsigned short bf16_rn(float x) {
    unsigned u = __float_as_uint(x);
    unsigned r = (u + 0x7FFFu + ((u >> 16) & 1u)) >> 16;
    return (unsigned short)r;
}
__device__ inline float bflo(unsigned u) { return __uint_as_float(u << 16); }
__device__ inline float bfhi(unsigned u) { return __uint_as_float(u & 0xFFFF0000u); }
__device__ inline float bfs(unsigned short h) { return __uint_as_float((unsigned)h << 16); }
__device__ inline float4 bf4tof(ushort4 h) {
    return make_float4(bfs(h.x), bfs(h.y), bfs(h.z), bfs(h.w));
}

// ---------------- degree ----------------
__global__ void k_deg(const int* __restrict__ dst, unsigned* __restrict__ deg, int E) {
    int e = blockIdx.x * 256 + threadIdx.x;
    if (e < E) atomicAdd(&deg[dst[e]], 1u);
}

// ---------------- hierarchical exclusive scan of deg -> rowptr (+dinv fold) ----------------
__global__ __launch_bounds__(1024) void k_scan1(const unsigned* __restrict__ deg,
                                                int* __restrict__ rowptr, int* __restrict__ bsum,
                                                float* __restrict__ dinv, int n) {
    __shared__ int wsum[16];
    int i = blockIdx.x * 1024 + threadIdx.x;
    int lane = threadIdx.x & 63, wid = threadIdx.x >> 6;
    int v = (i < n) ? (int)deg[i] : 0;
    if (i < n) dinv[i] = rsqrtf((float)v + 1.0f);     // +1 = self loop
    int incl = v;
    #pragma unroll
    for (int off = 1; off < 64; off <<= 1) {
        int t = __shfl_up(incl, off, 64);
        if (lane >= off) incl += t;
    }
    if (lane == 63) wsum[wid] = incl;
    __syncthreads();
    int woff = 0;
    #pragma unroll
    for (int w = 0; w < 16; ++w) woff += (w < wid) ? wsum[w] : 0;
    if (i < n) rowptr[i] = woff + incl - v;          // block-local exclusive
    if (threadIdx.x == 1023) bsum[blockIdx.x] = woff + incl;  // block total
}

__global__ void k_scan2(int* __restrict__ bsum, int* __restrict__ rowptr_n, int nb) {
    int lane = threadIdx.x;   // 64 threads, nb <= 64
    int v = (lane < nb) ? bsum[lane] : 0;
    int incl = v;
    #pragma unroll
    for (int off = 1; off < 64; off <<= 1) {
        int t = __shfl_up(incl, off, 64);
        if (lane >= off) incl += t;
    }
    if (lane < nb) bsum[lane] = incl - v;            // exclusive block offsets
    if (lane == 63) *rowptr_n = incl;                // grand total
}

__global__ __launch_bounds__(1024) void k_scan3(int* __restrict__ rowptr,
                                                const int* __restrict__ bsum,
                                                int* __restrict__ bcur, int n) {
    int i = blockIdx.x * 1024 + threadIdx.x;
    if (i < n) {
        int r = rowptr[i] + bsum[blockIdx.x];
        rowptr[i] = r;
        if ((i & 63) == 0) bcur[(i >> 6) * CPAD] = r;   // bucket cursor seed
    }
}

// ---------------- phase C: partition edges into 64-node buckets ----------------
__global__ __launch_bounds__(256) void k_binscatter(const int* __restrict__ src, const int* __restrict__ dst,
                                                    int* __restrict__ bcur, unsigned* __restrict__ tmp,
                                                    int E, int nbk) {
    __shared__ int hist[BKS];
    int tid = threadIdx.x;
    for (int b = tid; b < nbk; b += 256) hist[b] = 0;
    __syncthreads();
    int e0 = blockIdx.x * EPB;
    int s[16], d[16];
    #pragma unroll
    for (int i = 0; i < 16; ++i) {
        int e = e0 + i * 256 + tid;
        if (e < E) {
            s[i] = src[e]; d[i] = dst[e];
            atomicAdd(&hist[d[i] >> 6], 1);
        } else d[i] = -1;
    }
    __syncthreads();
    for (int b = tid; b < nbk; b += 256) {
        int c = hist[b];
        hist[b] = c ? atomicAdd(&bcur[b * CPAD], c) : 0;   // reserve dense run
    }
    __syncthreads();
    #pragma unroll
    for (int i = 0; i < 16; ++i) {
        if (d[i] >= 0) {
            int p = atomicAdd(&hist[d[i] >> 6], 1);
            tmp[p] = (unsigned)s[i] | ((unsigned)(d[i] & 63) << 16);   // n<=65536: src fits 16b
        }
    }
}

// ---------------- phase D: per-bucket fine sort into final CSR ----------------
__global__ __launch_bounds__(256) void k_finesort(const unsigned* __restrict__ tmp,
                                                  const int* __restrict__ rowptr,
                                                  int* __restrict__ csr_src, int n) {
    __shared__ int cur[64];
    int nb0 = blockIdx.x << 6;
    int tid = threadIdx.x;
    int hi = min(nb0 + 64, n);
    if (tid < 64 && nb0 + tid < n) cur[tid] = rowptr[nb0 + tid];
    __syncthreads();
    int estart = rowptr[nb0], eend = rowptr[hi];
    for (int e = estart + tid; e < eend; e += 256) {
        unsigned pr = tmp[e];
        int p = atomicAdd(&cur[(pr >> 16) & 63], 1);
        csr_src[p] = (int)(pr & 0xFFFFu);
    }
}

// ---------------- graph boundaries from sorted batch ----------------
__global__ void k_gptr(const int* __restrict__ batch, int* __restrict__ gptr, int n) {
    int g = blockIdx.x * 256 + threadIdx.x;
    if (g > GG) return;
    int lo = 0, hi = n;                       // first index with batch[i] >= g
    while (lo < hi) { int mid = (lo + hi) >> 1; if (batch[mid] < g) lo = mid + 1; else hi = mid; }
    gptr[g] = lo;
}

// ---------------- W prep: pack 3 layers of W into MFMA B-fragment order ----------------
__global__ void k_wprep(const float* __restrict__ W0, const float* __restrict__ W12,
                        unsigned short* __restrict__ Wt) {
    int t = blockIdx.x * 256 + threadIdx.x;          // 0 .. 3*16384-1
    int l = t >> 14, o = t & 16383;
    const float* W = (l == 0) ? W0 : W12 + (size_t)(l - 1) * 16384;
    int j = o & 7, c = (o >> 3) & 15, hi = (o >> 7) & 3, kb = (o >> 9) & 3, nt = o >> 11;
    int k = kb * 32 + hi * 8 + j;
    int col = nt * 16 + c;
    Wt[t] = bf16_rn(W[k * 128 + col]);
}

// ---------------- GEMM: H2 = bf16( (bn_relu(X) @ W) * dinv[row] ), MFMA ----------------
template<bool BF16IN>
__global__ __launch_bounds__(256) void k_gemm(const void* __restrict__ Xp,
                                              const unsigned short* __restrict__ Wt,
                                              const float* __restrict__ dinv,
                                              const float* __restrict__ sc,
                                              const float* __restrict__ sh,
                                              unsigned short* __restrict__ H, int n) {
    int wave = threadIdx.x >> 6, L = threadIdx.x & 63;
    int hi = L >> 4, c16 = L & 15;
    int m0 = blockIdx.x * 64 + wave * 16;
    int arow = m0 + c16;                   // A-frag row this lane loads
    bool okA = arow < n;

    short8v aF[4];
    #pragma unroll
    for (int kb = 0; kb < 4; ++kb) {
        int kc = kb * 32 + hi * 8;
        float v[8];
        #pragma unroll
        for (int j = 0; j < 8; ++j) v[j] = 0.f;
        if (okA) {
            if constexpr (BF16IN) {
                const unsigned short* Xb = (const unsigned short*)Xp;
                uint4 raw = *(const uint4*)&Xb[(size_t)arow * 128 + kc];
                v[0] = bflo(raw.x); v[1] = bfhi(raw.x);
                v[2] = bflo(raw.y); v[3] = bfhi(raw.y);
                v[4] = bflo(raw.z); v[5] = bfhi(raw.z);
                v[6] = bflo(raw.w); v[7] = bfhi(raw.w);
                float4 s0 = *(const float4*)&sc[kc], s1 = *(const float4*)&sc[kc + 4];
                float4 h0 = *(const float4*)&sh[kc], h1 = *(const float4*)&sh[kc + 4];
                v[0] = fmaxf(fmaf(v[0], s0.x, h0.x), 0.f);
                v[1] = fmaxf(fmaf(v[1], s0.y, h0.y), 0.f);
                v[2] = fmaxf(fmaf(v[2], s0.z, h0.z), 0.f);
                v[3] = fmaxf(fmaf(v[3], s0.w, h0.w), 0.f);
                v[4] = fmaxf(fmaf(v[4], s1.x, h1.x), 0.f);
                v[5] = fmaxf(fmaf(v[5], s1.y, h1.y), 0.f);
                v[6] = fmaxf(fmaf(v[6], s1.z, h1.z), 0.f);
                v[7] = fmaxf(fmaf(v[7], s1.w, h1.w), 0.f);
            } else {
                const float* Xf = (const float*)Xp;
                float4 v0 = *(const float4*)&Xf[(size_t)arow * 128 + kc];
                float4 v1 = *(const float4*)&Xf[(size_t)arow * 128 + kc + 4];
                v[0] = v0.x; v[1] = v0.y; v[2] = v0.z; v[3] = v0.w;
                v[4] = v1.x; v[5] = v1.y; v[6] = v1.z; v[7] = v1.w;
            }
        }
        short8v a;
        #pragma unroll
        for (int j = 0; j < 8; ++j) a[j] = (short)bf16_rn(v[j]);
        aF[kb] = a;
    }

    f32x4 acc[8];
    #pragma unroll
    for (int nt = 0; nt < 8; ++nt) {
        acc[nt][0] = 0.f; acc[nt][1] = 0.f; acc[nt][2] = 0.f; acc[nt][3] = 0.f;
    }
    #pragma unroll
    for (int nt = 0; nt < 8; ++nt) {
        #pragma unroll
        for (int kb = 0; kb < 4; ++kb) {
            short8v bF = *(const short8v*)&Wt[(size_t)(nt * 4 + kb) * 512 + L * 8];
            acc[nt] = __builtin_amdgcn_mfma_f32_16x16x32_bf16(aF[kb], bF, acc[nt], 0, 0, 0);
        }
    }

    // epilogue: C row = m0 + hi*4 + reg, col = nt*16 + c16
    #pragma unroll
    for (int reg = 0; reg < 4; ++reg) {
        int row = m0 + hi * 4 + reg;
        if (row < n) {
            float dv = dinv[row];
            #pragma unroll
            for (int nt = 0; nt < 8; ++nt)
                H[(size_t)row * 128 + nt * 16 + c16] = bf16_rn(acc[nt][reg] * dv);
        }
    }
}

// ---------------- pull aggregation + fused BN stats ----------------
// B[d] = bf16( dinv[d] * (H2[d] + sum H2[src]) ); per-block partial sum/sumsq
// of the rounded values accumulated in-register (saves a separate stats pass).
// 32 lanes/node (ushort4 = 4 feats each), 8 nodes/block-iteration, grid-stride.
__global__ __launch_bounds__(256) void k_aggstats(const int* __restrict__ rowptr, const int* __restrict__ csr_src,
                                                  const float* __restrict__ dinv,
                                                  const unsigned short* __restrict__ H2,
                                                  unsigned short* __restrict__ Bo,
                                                  float* __restrict__ partials, int n) {
    __shared__ float sb[8][128];
    int tid = threadIdx.x;
    int sub = tid >> 5, lane = tid & 31;
    const ushort4* Hv = (const ushort4*)H2;              // row = 32 ushort4
    float sA[4] = {0.f, 0.f, 0.f, 0.f}, qA[4] = {0.f, 0.f, 0.f, 0.f};
    for (int node = blockIdx.x * 8 + sub; node < n; node += NAB * 8) {
        int beg = rowptr[node], end = rowptr[node + 1];
        float dv = dinv[node];
        float4 acc = bf4tof(Hv[(size_t)node * 32 + lane]);   // self loop
        float4 acc2 = make_float4(0.f, 0.f, 0.f, 0.f);
        int e = beg;
        for (; e + 1 < end; e += 2) {
            int s0 = csr_src[e], s1 = csr_src[e + 1];
            float4 h0 = bf4tof(Hv[(size_t)s0 * 32 + lane]);
            float4 h1 = bf4tof(Hv[(size_t)s1 * 32 + lane]);
            acc.x += h0.x;  acc.y += h0.y;  acc.z += h0.z;  acc.w += h0.w;
            acc2.x += h1.x; acc2.y += h1.y; acc2.z += h1.z; acc2.w += h1.w;
        }
        if (e < end) {
            int s0 = csr_src[e];
            float4 h0 = bf4tof(Hv[(size_t)s0 * 32 + lane]);
            acc.x += h0.x; acc.y += h0.y; acc.z += h0.z; acc.w += h0.w;
        }
        ushort4 o;
        o.x = bf16_rn((acc.x + acc2.x) * dv);
        o.y = bf16_rn((acc.y + acc2.y) * dv);
        o.z = bf16_rn((acc.z + acc2.z) * dv);
        o.w = bf16_rn((acc.w + acc2.w) * dv);
        *(ushort4*)&Bo[(size_t)node * 128 + lane * 4] = o;
        float v0 = bfs(o.x), v1 = bfs(o.y), v2 = bfs(o.z), v3 = bfs(o.w);
        sA[0] += v0; qA[0] = fmaf(v0, v0, qA[0]);
        sA[1] += v1; qA[1] = fmaf(v1, v1, qA[1]);
        sA[2] += v2; qA[2] = fmaf(v2, v2, qA[2]);
        sA[3] += v3; qA[3] = fmaf(v3, v3, qA[3]);
    }
    #pragma unroll
    for (int j = 0; j < 4; ++j) sb[sub][lane * 4 + j] = sA[j];
    __syncthreads();
    if (tid < 128) partials[(size_t)blockIdx.x * 256 + tid] =
        sb[0][tid] + sb[1][tid] + sb[2][tid] + sb[3][tid] +
        sb[4][tid] + sb[5][tid] + sb[6][tid] + sb[7][tid];
    __syncthreads();
    #pragma unroll
    for (int j = 0; j < 4; ++j) sb[sub][lane * 4 + j] = qA[j];
    __syncthreads();
    if (tid < 128) partials[(size_t)blockIdx.x * 256 + 128 + tid] =
        sb[0][tid] + sb[1][tid] + sb[2][tid] + sb[3][tid] +
        sb[4][tid] + sb[5][tid] + sb[6][tid] + sb[7][tid];
}

// ---------------- finalize stats -> scale/shift (4-way split parallel reduce) ----------------
__global__ __launch_bounds__(512) void k_finstats(const float* __restrict__ partials,
                                                  const float* __restrict__ gamma, const float* __restrict__ beta,
                                                  float* __restrict__ sc, float* __restrict__ sh, int n) {
    __shared__ float red[512];
    int t = threadIdx.x;
    int f = t & 127, q4 = t >> 7;            // 4 quarters x NAB/4 blocks each
    float s = 0.f, q = 0.f;
    for (int b = q4 * (NAB / 4); b < (q4 + 1) * (NAB / 4); ++b) {
        s += partials[(size_t)b * 256 + f];
        q += partials[(size_t)b * 256 + 128 + f];
    }
    red[t] = s;
    __syncthreads();
    float s_tot = red[f] + red[f + 128] + red[f + 256] + red[f + 384];
    __syncthreads();
    red[t] = q;
    __syncthreads();
    if (q4 == 0) {
        float q_tot = red[f] + red[f + 128] + red[f + 256] + red[f + 384];
        float invN = 1.0f / (float)n;
        float mu = s_tot * invN;
        float var = fmaf(-mu, mu, q_tot * invN);
        float scale = gamma[f] * rsqrtf(var + EPSV);
        sc[f] = scale;
        sh[f] = fmaf(-mu, scale, beta[f]);
    }
}

// ---------------- pooling over sorted batch: mean & max, fused final BN+ReLU ----------------
__global__ __launch_bounds__(256) void k_pool(const unsigned short* __restrict__ X, const int* __restrict__ gptr,
                                              const float* __restrict__ sc, const float* __restrict__ sh,
                                              float* __restrict__ pooled) {
    __shared__ float shm[256];
    int g = blockIdx.x;
    int t = threadIdx.x;
    int f = t & 127, sub = t >> 7;
    int beg = gptr[g], end = gptr[g + 1];
    float scf = sc[f], shf = sh[f];
    float s = 0.f, m = 0.f;
    for (int r = beg + sub; r < end; r += 2) {
        float xv = bfs(X[(size_t)r * 128 + f]);
        float v = fmaxf(fmaf(xv, scf, shf), 0.f);
        s += v; m = fmaxf(m, v);
    }
    shm[t] = s;
    __syncthreads();
    if (sub == 0) {
        int c = end - beg;
        float inv = (c > 0) ? 1.0f / (float)c : 0.f;
        pooled[(size_t)g * 256 + f] = (s + shm[t + 128]) * inv;
    }
    __syncthreads();
    shm[t] = m;
    __syncthreads();
    if (sub == 1) {
        pooled[(size_t)g * 256 + 128 + f] = fmaxf(m, shm[t - 128]);  // 0 for empty graph = reference
    }
}

// ---------------- MLP ----------------
__global__ __launch_bounds__(256) void k_mlp1(const float* __restrict__ pooled, const float* __restrict__ W1,
                                              const float* __restrict__ b1, float* __restrict__ H1) {
    __shared__ float grow[256];
    int gi = blockIdx.x, t = threadIdx.x;
    grow[t] = pooled[(size_t)gi * 256 + t];
    __syncthreads();
    float acc = b1[t];
    #pragma unroll 8
    for (int k = 0; k < 256; ++k) acc = fmaf(grow[k], W1[k * 256 + t], acc);
    H1[gi * 256 + t] = fmaxf(acc, 0.f);
}

// fused mlp2 (256->128, relu) + mlp3 (128->1)
__global__ __launch_bounds__(128) void k_mlp23(const float* __restrict__ H1, const float* __restrict__ W2,
                                               const float* __restrict__ b2, const float* __restrict__ W3,
                                               const float* __restrict__ b3, float* __restrict__ out) {
    __shared__ float row[256];
    __shared__ float wred[2];
    int gi = blockIdx.x, t = threadIdx.x;
    row[t] = H1[gi * 256 + t];
    row[t + 128] = H1[gi * 256 + t + 128];
    __syncthreads();
    float acc = b2[t];
    #pragma unroll 8
    for (int k = 0; k < 256; ++k) acc = fmaf(row[k], W2[k * 128 + t], acc);
    float v = fmaxf(acc, 0.f) * W3[t];
    #pragma unroll
    for (int off = 32; off; off >>= 1) v += __shfl_down(v, off);
    if ((t & 63) == 0) wred[t >> 6] = v;
    __syncthreads();
    if (t == 0) out[gi] = wred[0] + wred[1] + b3[0];
}

extern "C" void kernel_launch(void* const* d_in, const int* in_sizes, int n_in,
                              void* d_out, int out_size, void* d_ws, size_t ws_size,
                              hipStream_t stream) {
    const float* x      = (const float*)d_in[0];
    const int*   ei     = (const int*)d_in[1];
    const int*   batch  = (const int*)d_in[2];
    const float* convW0 = (const float*)d_in[3];
    const float* convW  = (const float*)d_in[4];
    // d_in[5] convb: cancels inside BatchNorm, unused
    const float* gamma  = (const float*)d_in[6];
    const float* beta   = (const float*)d_in[7];
    const float* mW1    = (const float*)d_in[8];
    const float* mb1    = (const float*)d_in[9];
    const float* mW2    = (const float*)d_in[10];
    const float* mb2    = (const float*)d_in[11];
    const float* mW3    = (const float*)d_in[12];
    const float* mb3    = (const float*)d_in[13];
    float* out = (float*)d_out;

    const int E = in_sizes[1] / 2;
    const int n = in_sizes[0] / FH;
    const int npad = (n + 4) & ~3;
    const int nb = (n + 1023) / 1024;
    const int nbk = (n + 63) >> 6;            // 64-node buckets

    // workspace layout (16B-aligned chunks)
    float*          A     = (float*)d_ws;                     // n*128 f32 slot: bf16 H2; tmp overlays pre-loop
    unsigned short* H2b   = (unsigned short*)A;
    unsigned*       tmp   = (unsigned*)A;                     // E packed words (3.2MB), pre-loop only
    float*    B       = A + (size_t)n * FH;                   // n*128 f32 slot: bf16 B; bcur overlays pre-loop
    unsigned short* Bb = (unsigned short*)B;
    int*      bcur    = (int*)B;                              // nbk*CPAD ints (50KB), pre-loop only
    float*    dinv    = B + (size_t)n * FH;                   // n
    unsigned* deg     = (unsigned*)(dinv + n);                // n
    float*    parts   = (float*)(deg + n);                    // NAB*256
    float*    sc      = parts + (size_t)NAB * 256;            // 128
    float*    sh      = sc + 128;                             // 128
    float*    pooled  = sh + 128;                             // G*256
    float*    h1      = pooled + (size_t)GG * 256;            // G*256
    int*      gptr    = (int*)(h1 + (size_t)GG * 256);        // G+1 (pad 4)
    int*      rowptr  = gptr + ((GG + 4) & ~3);               // n+1 (padded)
    int*      bsum    = rowptr + npad;                        // 64
    int*      csrsrc  = bsum + 64;                            // E
    unsigned short* Wt = (unsigned short*)(csrsrc + ((E + 3) & ~3));  // 3*16384 ushorts

    const int* srcI = ei;
    const int* dstI = ei + E;

    // ---- CSR build (dense writes, low-contention atomics) + graph boundaries + W prep ----
    hipMemsetAsync(deg, 0, (size_t)n * sizeof(unsigned), stream);
    k_deg<<<(E + 255) / 256, 256, 0, stream>>>(dstI, deg, E);
    k_scan1<<<nb, 1024, 0, stream>>>(deg, rowptr, bsum, dinv, n);
    k_scan2<<<1, 64, 0, stream>>>(bsum, rowptr + n, nb);
    k_scan3<<<nb, 1024, 0, stream>>>(rowptr, bsum, bcur, n);
    k_binscatter<<<(E + EPB - 1) / EPB, 256, 0, stream>>>(srcI, dstI, bcur, tmp, E, nbk);
    k_finesort<<<nbk, 256, 0, stream>>>(tmp, rowptr, csrsrc, n);
    k_gptr<<<(GG + 1 + 255) / 256, 256, 0, stream>>>(batch, gptr, n);
    k_wprep<<<3 * 16384 / 256, 256, 0, stream>>>(convW0, convW, Wt);

    for (int l = 0; l < 3; ++l) {
        if (l == 0)
            k_gemm<false><<<(n + 63) / 64, 256, 0, stream>>>(x, Wt, dinv, nullptr, nullptr, H2b, n);
        else
            k_gemm<true><<<(n + 63) / 64, 256, 0, stream>>>(Bb, Wt + (size_t)l * 16384, dinv, sc, sh, H2b, n);
        k_aggstats<<<NAB, 256, 0, stream>>>(rowptr, csrsrc, dinv, H2b, Bb, parts, n);
        k_finstats<<<1, 512, 0, stream>>>(parts, gamma + l * FH, beta + l * FH, sc, sh, n);
    }

    // pooling (applies layer-3 BN+ReLU on the fly), then MLP
    k_pool<<<GG, 256, 0, stream>>>(Bb, gptr, sc, sh, pooled);
    k_mlp1<<<GG, 256, 0, stream>>>(pooled, mW1, mb1, h1);
    k_mlp23<<<GG, 128, 0, stream>>>(h1, mW2, mb2, mW3, mb3, out);
}

// Round 11
// 390.449 us; speedup vs baseline: 1.6070x; 1.6070x over previous
//
#include <hip/hip_runtime.h>

// GNN: 3x (GCNConv -> BN -> ReLU) -> mean/max pool per graph -> 3-layer MLP.
// N=50000 nodes, E=800000 edges, F=H=128, G=1024 graphs.
// conv bias cancels inside BatchNorm (mean-subtraction) -> skipped entirely.
// CSR build: block-level LDS histogram + one line-padded global cursor
// reservation per (block,bucket) -> dense packed-4B tmp scatter -> per-bucket
// LDS fine sort. No deep same-line atomic serialization anywhere.
// H2 and B activations stored bf16 (BN is self-consistent on bf16 values).
// GEMM: MFMA 16x16x32 bf16, no LDS; W pre-packed into fragment order.
// Aggregation fuses BN-stats accumulation; NAB=2048 blocks = full co-residency
// (round-10 lesson: 512 blocks = 19% occupancy starved the gather).
// BN-apply+ReLU folded into the NEXT consumer (GEMM staging / pooling).
// Pooling uses sorted `batch` (binary-searched boundaries) -> no atomics.

constexpr int FH = 128;     // feature dim
constexpr int GG = 1024;    // graphs
constexpr int NAB = 2048;   // aggregate blocks = 8 blocks/CU x 256 CU (co-residency limit)
constexpr int BKS = 1024;   // max 64-node buckets in LDS (n <= 65536; also needed for 16b src pack)
constexpr int CPAD = 16;    // global cursor padding in ints = one 64B line
constexpr int EPB = 4096;   // edges per partition block
constexpr float EPSV = 1e-5f;

typedef __attribute__((ext_vector_type(8))) short short8v;   // 8 bf16 (4 VGPRs)
typedef __attribute__((ext_vector_type(4))) float f32x4;     // MFMA acc

__device__ inline unsigned short bf16_rn(float x) {
    unsigned u = __float_as_uint(x);
    unsigned r = (u + 0x7FFFu + ((u >> 16) & 1u)) >> 16;
    return (unsigned short)r;
}
__device__ inline float bflo(unsigned u) { return __uint_as_float(u << 16); }
__device__ inline float bfhi(unsigned u) { return __uint_as_float(u & 0xFFFF0000u); }
__device__ inline float bfs(unsigned short h) { return __uint_as_float((unsigned)h << 16); }
__device__ inline float4 bf4tof(ushort4 h) {
    return make_float4(bfs(h.x), bfs(h.y), bfs(h.z), bfs(h.w));
}

// ---------------- degree ----------------
__global__ void k_deg(const int* __restrict__ dst, unsigned* __restrict__ deg, int E) {
    int e = blockIdx.x * 256 + threadIdx.x;
    if (e < E) atomicAdd(&deg[dst[e]], 1u);
}

// ---------------- hierarchical exclusive scan of deg -> rowptr (+dinv fold) ----------------
__global__ __launch_bounds__(1024) void k_scan1(const unsigned* __restrict__ deg,
                                                int* __restrict__ rowptr, int* __restrict__ bsum,
                                                float* __restrict__ dinv, int n) {
    __shared__ int wsum[16];
    int i = blockIdx.x * 1024 + threadIdx.x;
    int lane = threadIdx.x & 63, wid = threadIdx.x >> 6;
    int v = (i < n) ? (int)deg[i] : 0;
    if (i < n) dinv[i] = rsqrtf((float)v + 1.0f);     // +1 = self loop
    int incl = v;
    #pragma unroll
    for (int off = 1; off < 64; off <<= 1) {
        int t = __shfl_up(incl, off, 64);
        if (lane >= off) incl += t;
    }
    if (lane == 63) wsum[wid] = incl;
    __syncthreads();
    int woff = 0;
    #pragma unroll
    for (int w = 0; w < 16; ++w) woff += (w < wid) ? wsum[w] : 0;
    if (i < n) rowptr[i] = woff + incl - v;          // block-local exclusive
    if (threadIdx.x == 1023) bsum[blockIdx.x] = woff + incl;  // block total
}

__global__ void k_scan2(int* __restrict__ bsum, int* __restrict__ rowptr_n, int nb) {
    int lane = threadIdx.x;   // 64 threads, nb <= 64
    int v = (lane < nb) ? bsum[lane] : 0;
    int incl = v;
    #pragma unroll
    for (int off = 1; off < 64; off <<= 1) {
        int t = __shfl_up(incl, off, 64);
        if (lane >= off) incl += t;
    }
    if (lane < nb) bsum[lane] = incl - v;            // exclusive block offsets
    if (lane == 63) *rowptr_n = incl;                // grand total
}

__global__ __launch_bounds__(1024) void k_scan3(int* __restrict__ rowptr,
                                                const int* __restrict__ bsum,
                                                int* __restrict__ bcur, int n) {
    int i = blockIdx.x * 1024 + threadIdx.x;
    if (i < n) {
        int r = rowptr[i] + bsum[blockIdx.x];
        rowptr[i] = r;
        if ((i & 63) == 0) bcur[(i >> 6) * CPAD] = r;   // bucket cursor seed
    }
}

// ---------------- phase C: partition edges into 64-node buckets ----------------
__global__ __launch_bounds__(256) void k_binscatter(const int* __restrict__ src, const int* __restrict__ dst,
                                                    int* __restrict__ bcur, unsigned* __restrict__ tmp,
                                                    int E, int nbk) {
    __shared__ int hist[BKS];
    int tid = threadIdx.x;
    for (int b = tid; b < nbk; b += 256) hist[b] = 0;
    __syncthreads();
    int e0 = blockIdx.x * EPB;
    int s[16], d[16];
    #pragma unroll
    for (int i = 0; i < 16; ++i) {
        int e = e0 + i * 256 + tid;
        if (e < E) {
            s[i] = src[e]; d[i] = dst[e];
            atomicAdd(&hist[d[i] >> 6], 1);
        } else d[i] = -1;
    }
    __syncthreads();
    for (int b = tid; b < nbk; b += 256) {
        int c = hist[b];
        hist[b] = c ? atomicAdd(&bcur[b * CPAD], c) : 0;   // reserve dense run
    }
    __syncthreads();
    #pragma unroll
    for (int i = 0; i < 16; ++i) {
        if (d[i] >= 0) {
            int p = atomicAdd(&hist[d[i] >> 6], 1);
            tmp[p] = (unsigned)s[i] | ((unsigned)(d[i] & 63) << 16);   // n<=65536: src fits 16b
        }
    }
}

// ---------------- phase D: per-bucket fine sort into final CSR ----------------
__global__ __launch_bounds__(256) void k_finesort(const unsigned* __restrict__ tmp,
                                                  const int* __restrict__ rowptr,
                                                  int* __restrict__ csr_src, int n) {
    __shared__ int cur[64];
    int nb0 = blockIdx.x << 6;
    int tid = threadIdx.x;
    int hi = min(nb0 + 64, n);
    if (tid < 64 && nb0 + tid < n) cur[tid] = rowptr[nb0 + tid];
    __syncthreads();
    int estart = rowptr[nb0], eend = rowptr[hi];
    for (int e = estart + tid; e < eend; e += 256) {
        unsigned pr = tmp[e];
        int p = atomicAdd(&cur[(pr >> 16) & 63], 1);
        csr_src[p] = (int)(pr & 0xFFFFu);
    }
}

// ---------------- graph boundaries from sorted batch ----------------
__global__ void k_gptr(const int* __restrict__ batch, int* __restrict__ gptr, int n) {
    int g = blockIdx.x * 256 + threadIdx.x;
    if (g > GG) return;
    int lo = 0, hi = n;                       // first index with batch[i] >= g
    while (lo < hi) { int mid = (lo + hi) >> 1; if (batch[mid] < g) lo = mid + 1; else hi = mid; }
    gptr[g] = lo;
}

// ---------------- W prep: pack 3 layers of W into MFMA B-fragment order ----------------
__global__ void k_wprep(const float* __restrict__ W0, const float* __restrict__ W12,
                        unsigned short* __restrict__ Wt) {
    int t = blockIdx.x * 256 + threadIdx.x;          // 0 .. 3*16384-1
    int l = t >> 14, o = t & 16383;
    const float* W = (l == 0) ? W0 : W12 + (size_t)(l - 1) * 16384;
    int j = o & 7, c = (o >> 3) & 15, hi = (o >> 7) & 3, kb = (o >> 9) & 3, nt = o >> 11;
    int k = kb * 32 + hi * 8 + j;
    int col = nt * 16 + c;
    Wt[t] = bf16_rn(W[k * 128 + col]);
}

// ---------------- GEMM: H2 = bf16( (bn_relu(X) @ W) * dinv[row] ), MFMA ----------------
template<bool BF16IN>
__global__ __launch_bounds__(256) void k_gemm(const void* __restrict__ Xp,
                                              const unsigned short* __restrict__ Wt,
                                              const float* __restrict__ dinv,
                                              const float* __restrict__ sc,
                                              const float* __restrict__ sh,
                                              unsigned short* __restrict__ H, int n) {
    int wave = threadIdx.x >> 6, L = threadIdx.x & 63;
    int hi = L >> 4, c16 = L & 15;
    int m0 = blockIdx.x * 64 + wave * 16;
    int arow = m0 + c16;                   // A-frag row this lane loads
    bool okA = arow < n;

    short8v aF[4];
    #pragma unroll
    for (int kb = 0; kb < 4; ++kb) {
        int kc = kb * 32 + hi * 8;
        float v[8];
        #pragma unroll
        for (int j = 0; j < 8; ++j) v[j] = 0.f;
        if (okA) {
            if constexpr (BF16IN) {
                const unsigned short* Xb = (const unsigned short*)Xp;
                uint4 raw = *(const uint4*)&Xb[(size_t)arow * 128 + kc];
                v[0] = bflo(raw.x); v[1] = bfhi(raw.x);
                v[2] = bflo(raw.y); v[3] = bfhi(raw.y);
                v[4] = bflo(raw.z); v[5] = bfhi(raw.z);
                v[6] = bflo(raw.w); v[7] = bfhi(raw.w);
                float4 s0 = *(const float4*)&sc[kc], s1 = *(const float4*)&sc[kc + 4];
                float4 h0 = *(const float4*)&sh[kc], h1 = *(const float4*)&sh[kc + 4];
                v[0] = fmaxf(fmaf(v[0], s0.x, h0.x), 0.f);
                v[1] = fmaxf(fmaf(v[1], s0.y, h0.y), 0.f);
                v[2] = fmaxf(fmaf(v[2], s0.z, h0.z), 0.f);
                v[3] = fmaxf(fmaf(v[3], s0.w, h0.w), 0.f);
                v[4] = fmaxf(fmaf(v[4], s1.x, h1.x), 0.f);
                v[5] = fmaxf(fmaf(v[5], s1.y, h1.y), 0.f);
                v[6] = fmaxf(fmaf(v[6], s1.z, h1.z), 0.f);
                v[7] = fmaxf(fmaf(v[7], s1.w, h1.w), 0.f);
            } else {
                const float* Xf = (const float*)Xp;
                float4 v0 = *(const float4*)&Xf[(size_t)arow * 128 + kc];
                float4 v1 = *(const float4*)&Xf[(size_t)arow * 128 + kc + 4];
                v[0] = v0.x; v[1] = v0.y; v[2] = v0.z; v[3] = v0.w;
                v[4] = v1.x; v[5] = v1.y; v[6] = v1.z; v[7] = v1.w;
            }
        }
        short8v a;
        #pragma unroll
        for (int j = 0; j < 8; ++j) a[j] = (short)bf16_rn(v[j]);
        aF[kb] = a;
    }

    f32x4 acc[8];
    #pragma unroll
    for (int nt = 0; nt < 8; ++nt) {
        acc[nt][0] = 0.f; acc[nt][1] = 0.f; acc[nt][2] = 0.f; acc[nt][3] = 0.f;
    }
    #pragma unroll
    for (int nt = 0; nt < 8; ++nt) {
        #pragma unroll
        for (int kb = 0; kb < 4; ++kb) {
            short8v bF = *(const short8v*)&Wt[(size_t)(nt * 4 + kb) * 512 + L * 8];
            acc[nt] = __builtin_amdgcn_mfma_f32_16x16x32_bf16(aF[kb], bF, acc[nt], 0, 0, 0);
        }
    }

    // epilogue: C row = m0 + hi*4 + reg, col = nt*16 + c16
    #pragma unroll
    for (int reg = 0; reg < 4; ++reg) {
        int row = m0 + hi * 4 + reg;
        if (row < n) {
            float dv = dinv[row];
            #pragma unroll
            for (int nt = 0; nt < 8; ++nt)
                H[(size_t)row * 128 + nt * 16 + c16] = bf16_rn(acc[nt][reg] * dv);
        }
    }
}

// ---------------- pull aggregation + fused BN stats ----------------
// B[d] = bf16( dinv[d] * (H2[d] + sum H2[src]) ); per-block partial sum/sumsq
// of the rounded values accumulated in-register (saves a separate stats pass).
// 32 lanes/node (ushort4 = 4 feats each), 8 nodes/block-iteration, grid-stride.
__global__ __launch_bounds__(256) void k_aggstats(const int* __restrict__ rowptr, const int* __restrict__ csr_src,
                                                  const float* __restrict__ dinv,
                                                  const unsigned short* __restrict__ H2,
                                                  unsigned short* __restrict__ Bo,
                                                  float* __restrict__ partials, int n) {
    __shared__ float sb[8][128];
    int tid = threadIdx.x;
    int sub = tid >> 5, lane = tid & 31;
    const ushort4* Hv = (const ushort4*)H2;              // row = 32 ushort4
    float sA[4] = {0.f, 0.f, 0.f, 0.f}, qA[4] = {0.f, 0.f, 0.f, 0.f};
    for (int node = blockIdx.x * 8 + sub; node < n; node += NAB * 8) {
        int beg = rowptr[node], end = rowptr[node + 1];
        float dv = dinv[node];
        float4 acc = bf4tof(Hv[(size_t)node * 32 + lane]);   // self loop
        float4 acc2 = make_float4(0.f, 0.f, 0.f, 0.f);
        int e = beg;
        for (; e + 1 < end; e += 2) {
            int s0 = csr_src[e], s1 = csr_src[e + 1];
            float4 h0 = bf4tof(Hv[(size_t)s0 * 32 + lane]);
            float4 h1 = bf4tof(Hv[(size_t)s1 * 32 + lane]);
            acc.x += h0.x;  acc.y += h0.y;  acc.z += h0.z;  acc.w += h0.w;
            acc2.x += h1.x; acc2.y += h1.y; acc2.z += h1.z; acc2.w += h1.w;
        }
        if (e < end) {
            int s0 = csr_src[e];
            float4 h0 = bf4tof(Hv[(size_t)s0 * 32 + lane]);
            acc.x += h0.x; acc.y += h0.y; acc.z += h0.z; acc.w += h0.w;
        }
        ushort4 o;
        o.x = bf16_rn((acc.x + acc2.x) * dv);
        o.y = bf16_rn((acc.y + acc2.y) * dv);
        o.z = bf16_rn((acc.z + acc2.z) * dv);
        o.w = bf16_rn((acc.w + acc2.w) * dv);
        *(ushort4*)&Bo[(size_t)node * 128 + lane * 4] = o;
        float v0 = bfs(o.x), v1 = bfs(o.y), v2 = bfs(o.z), v3 = bfs(o.w);
        sA[0] += v0; qA[0] = fmaf(v0, v0, qA[0]);
        sA[1] += v1; qA[1] = fmaf(v1, v1, qA[1]);
        sA[2] += v2; qA[2] = fmaf(v2, v2, qA[2]);
        sA[3] += v3; qA[3] = fmaf(v3, v3, qA[3]);
    }
    #pragma unroll
    for (int j = 0; j < 4; ++j) sb[sub][lane * 4 + j] = sA[j];
    __syncthreads();
    if (tid < 128) partials[(size_t)blockIdx.x * 256 + tid] =
        sb[0][tid] + sb[1][tid] + sb[2][tid] + sb[3][tid] +
        sb[4][tid] + sb[5][tid] + sb[6][tid] + sb[7][tid];
    __syncthreads();
    #pragma unroll
    for (int j = 0; j < 4; ++j) sb[sub][lane * 4 + j] = qA[j];
    __syncthreads();
    if (tid < 128) partials[(size_t)blockIdx.x * 256 + 128 + tid] =
        sb[0][tid] + sb[1][tid] + sb[2][tid] + sb[3][tid] +
        sb[4][tid] + sb[5][tid] + sb[6][tid] + sb[7][tid];
}

// ---------------- finalize stats: one block per feature, parallel over NAB partials ----------------
__global__ __launch_bounds__(256) void k_finstats(const float* __restrict__ partials,
                                                  const float* __restrict__ gamma, const float* __restrict__ beta,
                                                  float* __restrict__ sc, float* __restrict__ sh, int n) {
    __shared__ float red[256];
    int f = blockIdx.x;                       // 0..127
    int t = threadIdx.x;
    int half = t >> 7, idx = t & 127;         // half 0: sum, half 1: sumsq
    float acc = 0.f;
    for (int b = idx; b < NAB; b += 128)
        acc += partials[(size_t)b * 256 + half * 128 + f];
    red[t] = acc;
    __syncthreads();
    #pragma unroll
    for (int off = 64; off; off >>= 1) {
        if (idx < off) red[t] += red[t + off];
        __syncthreads();
    }
    if (t == 0) {
        float s = red[0], q = red[128];
        float invN = 1.0f / (float)n;
        float mu = s * invN;
        float var = fmaf(-mu, mu, q * invN);
        float scale = gamma[f] * rsqrtf(var + EPSV);
        sc[f] = scale;
        sh[f] = fmaf(-mu, scale, beta[f]);
    }
}

// ---------------- pooling over sorted batch: mean & max, fused final BN+ReLU ----------------
__global__ __launch_bounds__(256) void k_pool(const unsigned short* __restrict__ X, const int* __restrict__ gptr,
                                              const float* __restrict__ sc, const float* __restrict__ sh,
                                              float* __restrict__ pooled) {
    __shared__ float shm[256];
    int g = blockIdx.x;
    int t = threadIdx.x;
    int f = t & 127, sub = t >> 7;
    int beg = gptr[g], end = gptr[g + 1];
    float scf = sc[f], shf = sh[f];
    float s = 0.f, m = 0.f;
    for (int r = beg + sub; r < end; r += 2) {
        float xv = bfs(X[(size_t)r * 128 + f]);
        float v = fmaxf(fmaf(xv, scf, shf), 0.f);
        s += v; m = fmaxf(m, v);
    }
    shm[t] = s;
    __syncthreads();
    if (sub == 0) {
        int c = end - beg;
        float inv = (c > 0) ? 1.0f / (float)c : 0.f;
        pooled[(size_t)g * 256 + f] = (s + shm[t + 128]) * inv;
    }
    __syncthreads();
    shm[t] = m;
    __syncthreads();
    if (sub == 1) {
        pooled[(size_t)g * 256 + 128 + f] = fmaxf(m, shm[t - 128]);  // 0 for empty graph = reference
    }
}

// ---------------- MLP ----------------
__global__ __launch_bounds__(256) void k_mlp1(const float* __restrict__ pooled, const float* __restrict__ W1,
                                              const float* __restrict__ b1, float* __restrict__ H1) {
    __shared__ float grow[256];
    int gi = blockIdx.x, t = threadIdx.x;
    grow[t] = pooled[(size_t)gi * 256 + t];
    __syncthreads();
    float acc = b1[t];
    #pragma unroll 8
    for (int k = 0; k < 256; ++k) acc = fmaf(grow[k], W1[k * 256 + t], acc);
    H1[gi * 256 + t] = fmaxf(acc, 0.f);
}

// fused mlp2 (256->128, relu) + mlp3 (128->1)
__global__ __launch_bounds__(128) void k_mlp23(const float* __restrict__ H1, const float* __restrict__ W2,
                                               const float* __restrict__ b2, const float* __restrict__ W3,
                                               const float* __restrict__ b3, float* __restrict__ out) {
    __shared__ float row[256];
    __shared__ float wred[2];
    int gi = blockIdx.x, t = threadIdx.x;
    row[t] = H1[gi * 256 + t];
    row[t + 128] = H1[gi * 256 + t + 128];
    __syncthreads();
    float acc = b2[t];
    #pragma unroll 8
    for (int k = 0; k < 256; ++k) acc = fmaf(row[k], W2[k * 128 + t], acc);
    float v = fmaxf(acc, 0.f) * W3[t];
    #pragma unroll
    for (int off = 32; off; off >>= 1) v += __shfl_down(v, off);
    if ((t & 63) == 0) wred[t >> 6] = v;
    __syncthreads();
    if (t == 0) out[gi] = wred[0] + wred[1] + b3[0];
}

extern "C" void kernel_launch(void* const* d_in, const int* in_sizes, int n_in,
                              void* d_out, int out_size, void* d_ws, size_t ws_size,
                              hipStream_t stream) {
    const float* x      = (const float*)d_in[0];
    const int*   ei     = (const int*)d_in[1];
    const int*   batch  = (const int*)d_in[2];
    const float* convW0 = (const float*)d_in[3];
    const float* convW  = (const float*)d_in[4];
    // d_in[5] convb: cancels inside BatchNorm, unused
    const float* gamma  = (const float*)d_in[6];
    const float* beta   = (const float*)d_in[7];
    const float* mW1    = (const float*)d_in[8];
    const float* mb1    = (const float*)d_in[9];
    const float* mW2    = (const float*)d_in[10];
    const float* mb2    = (const float*)d_in[11];
    const float* mW3    = (const float*)d_in[12];
    const float* mb3    = (const float*)d_in[13];
    float* out = (float*)d_out;

    const int E = in_sizes[1] / 2;
    const int n = in_sizes[0] / FH;
    const int npad = (n + 4) & ~3;
    const int nb = (n + 1023) / 1024;
    const int nbk = (n + 63) >> 6;            // 64-node buckets

    // workspace layout (16B-aligned chunks)
    float*          A     = (float*)d_ws;                     // n*128 f32 slot: bf16 H2; tmp overlays pre-loop
    unsigned short* H2b   = (unsigned short*)A;
    unsigned*       tmp   = (unsigned*)A;                     // E packed words (3.2MB), pre-loop only
    float*    B       = A + (size_t)n * FH;                   // n*128 f32 slot: bf16 B; bcur overlays pre-loop
    unsigned short* Bb = (unsigned short*)B;
    int*      bcur    = (int*)B;                              // nbk*CPAD ints (50KB), pre-loop only
    float*    dinv    = B + (size_t)n * FH;                   // n
    unsigned* deg     = (unsigned*)(dinv + n);                // n
    float*    parts   = (float*)(deg + n);                    // NAB*256 (2MB)
    float*    sc      = parts + (size_t)NAB * 256;            // 128
    float*    sh      = sc + 128;                             // 128
    float*    pooled  = sh + 128;                             // G*256
    float*    h1      = pooled + (size_t)GG * 256;            // G*256
    int*      gptr    = (int*)(h1 + (size_t)GG * 256);        // G+1 (pad 4)
    int*      rowptr  = gptr + ((GG + 4) & ~3);               // n+1 (padded)
    int*      bsum    = rowptr + npad;                        // 64
    int*      csrsrc  = bsum + 64;                            // E
    unsigned short* Wt = (unsigned short*)(csrsrc + ((E + 3) & ~3));  // 3*16384 ushorts

    const int* srcI = ei;
    const int* dstI = ei + E;

    // ---- CSR build (dense writes, low-contention atomics) + graph boundaries + W prep ----
    hipMemsetAsync(deg, 0, (size_t)n * sizeof(unsigned), stream);
    k_deg<<<(E + 255) / 256, 256, 0, stream>>>(dstI, deg, E);
    k_scan1<<<nb, 1024, 0, stream>>>(deg, rowptr, bsum, dinv, n);
    k_scan2<<<1, 64, 0, stream>>>(bsum, rowptr + n, nb);
    k_scan3<<<nb, 1024, 0, stream>>>(rowptr, bsum, bcur, n);
    k_binscatter<<<(E + EPB - 1) / EPB, 256, 0, stream>>>(srcI, dstI, bcur, tmp, E, nbk);
    k_finesort<<<nbk, 256, 0, stream>>>(tmp, rowptr, csrsrc, n);
    k_gptr<<<(GG + 1 + 255) / 256, 256, 0, stream>>>(batch, gptr, n);
    k_wprep<<<3 * 16384 / 256, 256, 0, stream>>>(convW0, convW, Wt);

    for (int l = 0; l < 3; ++l) {
        if (l == 0)
            k_gemm<false><<<(n + 63) / 64, 256, 0, stream>>>(x, Wt, dinv, nullptr, nullptr, H2b, n);
        else
            k_gemm<true><<<(n + 63) / 64, 256, 0, stream>>>(Bb, Wt + (size_t)l * 16384, dinv, sc, sh, H2b, n);
        k_aggstats<<<NAB, 256, 0, stream>>>(rowptr, csrsrc, dinv, H2b, Bb, parts, n);
        k_finstats<<<FH, 256, 0, stream>>>(parts, gamma + l * FH, beta + l * FH, sc, sh, n);
    }

    // pooling (applies layer-3 BN+ReLU on the fly), then MLP
    k_pool<<<GG, 256, 0, stream>>>(Bb, gptr, sc, sh, pooled);
    k_mlp1<<<GG, 256, 0, stream>>>(pooled, mW1, mb1, h1);
    k_mlp23<<<GG, 128, 0, stream>>>(h1, mW2, mb2, mW3, mb3, out);
}

// Round 12
// 371.178 us; speedup vs baseline: 1.6904x; 1.0519x over previous
//
#include <hip/hip_runtime.h>

// GNN: 3x (GCNConv -> BN -> ReLU) -> mean/max pool per graph -> 3-layer MLP.
// N=50000 nodes, E=800000 edges, F=H=128, G=1024 graphs.
// conv bias cancels inside BatchNorm (mean-subtraction) -> skipped entirely.
// CSR build: block-level LDS histogram + one line-padded global cursor
// reservation per (block,bucket) -> dense packed-4B tmp scatter -> per-bucket
// LDS fine sort. No deep same-line atomic serialization anywhere.
// H2 and B activations stored bf16 (BN is self-consistent on bf16 values).
// GEMM: MFMA 16x16x32 bf16, no LDS; W pre-packed into fragment order.
// Aggregation fuses BN-stats accumulation; NAB=2048 = full co-residency.
// BN-apply+ReLU folded into the NEXT consumer (GEMM staging / tail pooling).
// Dispatch-count minimized: setup fused (deg+gptr+wprep), scan2 absorbed
// into scan3, tail fused (pool+mlp1+mlp2+mlp3). 16 dispatches/iteration.

constexpr int FH = 128;     // feature dim
constexpr int GG = 1024;    // graphs
constexpr int NAB = 2048;   // aggregate blocks = 8 blocks/CU x 256 CU (co-residency limit)
constexpr int BKS = 1024;   // max 64-node buckets in LDS (n <= 65536; also needed for 16b src pack)
constexpr int CPAD = 16;    // global cursor padding in ints = one 64B line
constexpr int EPB = 4096;   // edges per partition block
constexpr float EPSV = 1e-5f;

typedef __attribute__((ext_vector_type(8))) short short8v;   // 8 bf16 (4 VGPRs)
typedef __attribute__((ext_vector_type(4))) float f32x4;     // MFMA acc

__device__ inline unsigned short bf16_rn(float x) {
    unsigned u = __float_as_uint(x);
    unsigned r = (u + 0x7FFFu + ((u >> 16) & 1u)) >> 16;
    return (unsigned short)r;
}
__device__ inline float bflo(unsigned u) { return __uint_as_float(u << 16); }
__device__ inline float bfhi(unsigned u) { return __uint_as_float(u & 0xFFFF0000u); }
__device__ inline float bfs(unsigned short h) { return __uint_as_float((unsigned)h << 16); }
__device__ inline float4 bf4tof(ushort4 h) {
    return make_float4(bfs(h.x), bfs(h.y), bfs(h.z), bfs(h.w));
}

// ---------------- fused setup: degree count | graph boundaries | W pack ----------------
// block ranges: [0, degB) edge-degree atomics; [degB, degB+gptrB) batch binary
// search; [degB+gptrB, ...) W fragment packing. All independent.
__global__ __launch_bounds__(256) void k_setup(const int* __restrict__ dst, unsigned* __restrict__ deg, int E,
                                               const int* __restrict__ batch, int* __restrict__ gptr, int n,
                                               const float* __restrict__ W0, const float* __restrict__ W12,
                                               unsigned short* __restrict__ Wt, int degB, int gptrB) {
    int b = blockIdx.x;
    if (b < degB) {
        int e = b * 256 + threadIdx.x;
        if (e < E) atomicAdd(&deg[dst[e]], 1u);
    } else if (b < degB + gptrB) {
        int g = (b - degB) * 256 + threadIdx.x;
        if (g > GG) return;
        int lo = 0, hi = n;                   // first index with batch[i] >= g
        while (lo < hi) { int mid = (lo + hi) >> 1; if (batch[mid] < g) lo = mid + 1; else hi = mid; }
        gptr[g] = lo;
    } else {
        int t = (b - degB - gptrB) * 256 + threadIdx.x;   // 0 .. 3*16384-1
        int l = t >> 14, o = t & 16383;
        const float* W = (l == 0) ? W0 : W12 + (size_t)(l - 1) * 16384;
        int j = o & 7, c = (o >> 3) & 15, hi = (o >> 7) & 3, kb = (o >> 9) & 3, nt = o >> 11;
        Wt[t] = bf16_rn(W[(kb * 32 + hi * 8 + j) * 128 + nt * 16 + c]);
    }
}

// ---------------- scan pass 1: block-local exclusive scan of deg (+dinv fold) ----------------
__global__ __launch_bounds__(1024) void k_scan1(const unsigned* __restrict__ deg,
                                                int* __restrict__ rowptr, int* __restrict__ bsum,
                                                float* __restrict__ dinv, int n) {
    __shared__ int wsum[16];
    int i = blockIdx.x * 1024 + threadIdx.x;
    int lane = threadIdx.x & 63, wid = threadIdx.x >> 6;
    int v = (i < n) ? (int)deg[i] : 0;
    if (i < n) dinv[i] = rsqrtf((float)v + 1.0f);     // +1 = self loop
    int incl = v;
    #pragma unroll
    for (int off = 1; off < 64; off <<= 1) {
        int t = __shfl_up(incl, off, 64);
        if (lane >= off) incl += t;
    }
    if (lane == 63) wsum[wid] = incl;
    __syncthreads();
    int woff = 0;
    #pragma unroll
    for (int w = 0; w < 16; ++w) woff += (w < wid) ? wsum[w] : 0;
    if (i < n) rowptr[i] = woff + incl - v;          // block-local exclusive
    if (threadIdx.x == 1023) bsum[blockIdx.x] = woff + incl;  // block total
}

// ---------------- scan pass 2 (absorbs old scan2): add block offsets, seed bcur, write rowptr[n] ----------------
__global__ __launch_bounds__(1024) void k_scan3(int* __restrict__ rowptr,
                                                const int* __restrict__ bsum,
                                                const unsigned* __restrict__ deg,
                                                int* __restrict__ bcur, int n) {
    __shared__ int s_off;
    if (threadIdx.x == 0) {
        int off = 0;
        for (int w = 0; w < (int)blockIdx.x; ++w) off += bsum[w];   // <=48 L2-hot reads
        s_off = off;
    }
    __syncthreads();
    int i = blockIdx.x * 1024 + threadIdx.x;
    if (i < n) {
        int r = rowptr[i] + s_off;
        rowptr[i] = r;
        if ((i & 63) == 0) bcur[(i >> 6) * CPAD] = r;   // bucket cursor seed
        if (i == n - 1) rowptr[n] = r + (int)deg[i];    // grand total = E
    }
}

// ---------------- phase C: partition edges into 64-node buckets ----------------
__global__ __launch_bounds__(256) void k_binscatter(const int* __restrict__ src, const int* __restrict__ dst,
                                                    int* __restrict__ bcur, unsigned* __restrict__ tmp,
                                                    int E, int nbk) {
    __shared__ int hist[BKS];
    int tid = threadIdx.x;
    for (int b = tid; b < nbk; b += 256) hist[b] = 0;
    __syncthreads();
    int e0 = blockIdx.x * EPB;
    int s[16], d[16];
    #pragma unroll
    for (int i = 0; i < 16; ++i) {
        int e = e0 + i * 256 + tid;
        if (e < E) {
            s[i] = src[e]; d[i] = dst[e];
            atomicAdd(&hist[d[i] >> 6], 1);
        } else d[i] = -1;
    }
    __syncthreads();
    for (int b = tid; b < nbk; b += 256) {
        int c = hist[b];
        hist[b] = c ? atomicAdd(&bcur[b * CPAD], c) : 0;   // reserve dense run
    }
    __syncthreads();
    #pragma unroll
    for (int i = 0; i < 16; ++i) {
        if (d[i] >= 0) {
            int p = atomicAdd(&hist[d[i] >> 6], 1);
            tmp[p] = (unsigned)s[i] | ((unsigned)(d[i] & 63) << 16);   // n<=65536: src fits 16b
        }
    }
}

// ---------------- phase D: per-bucket fine sort into final CSR ----------------
__global__ __launch_bounds__(256) void k_finesort(const unsigned* __restrict__ tmp,
                                                  const int* __restrict__ rowptr,
                                                  int* __restrict__ csr_src, int n) {
    __shared__ int cur[64];
    int nb0 = blockIdx.x << 6;
    int tid = threadIdx.x;
    int hi = min(nb0 + 64, n);
    if (tid < 64 && nb0 + tid < n) cur[tid] = rowptr[nb0 + tid];
    __syncthreads();
    int estart = rowptr[nb0], eend = rowptr[hi];
    for (int e = estart + tid; e < eend; e += 256) {
        unsigned pr = tmp[e];
        int p = atomicAdd(&cur[(pr >> 16) & 63], 1);
        csr_src[p] = (int)(pr & 0xFFFFu);
    }
}

// ---------------- GEMM: H2 = bf16( (bn_relu(X) @ W) * dinv[row] ), MFMA ----------------
template<bool BF16IN>
__global__ __launch_bounds__(256) void k_gemm(const void* __restrict__ Xp,
                                              const unsigned short* __restrict__ Wt,
                                              const float* __restrict__ dinv,
                                              const float* __restrict__ sc,
                                              const float* __restrict__ sh,
                                              unsigned short* __restrict__ H, int n) {
    int wave = threadIdx.x >> 6, L = threadIdx.x & 63;
    int hi = L >> 4, c16 = L & 15;
    int m0 = blockIdx.x * 64 + wave * 16;
    int arow = m0 + c16;                   // A-frag row this lane loads
    bool okA = arow < n;

    short8v aF[4];
    #pragma unroll
    for (int kb = 0; kb < 4; ++kb) {
        int kc = kb * 32 + hi * 8;
        float v[8];
        #pragma unroll
        for (int j = 0; j < 8; ++j) v[j] = 0.f;
        if (okA) {
            if constexpr (BF16IN) {
                const unsigned short* Xb = (const unsigned short*)Xp;
                uint4 raw = *(const uint4*)&Xb[(size_t)arow * 128 + kc];
                v[0] = bflo(raw.x); v[1] = bfhi(raw.x);
                v[2] = bflo(raw.y); v[3] = bfhi(raw.y);
                v[4] = bflo(raw.z); v[5] = bfhi(raw.z);
                v[6] = bflo(raw.w); v[7] = bfhi(raw.w);
                float4 s0 = *(const float4*)&sc[kc], s1 = *(const float4*)&sc[kc + 4];
                float4 h0 = *(const float4*)&sh[kc], h1 = *(const float4*)&sh[kc + 4];
                v[0] = fmaxf(fmaf(v[0], s0.x, h0.x), 0.f);
                v[1] = fmaxf(fmaf(v[1], s0.y, h0.y), 0.f);
                v[2] = fmaxf(fmaf(v[2], s0.z, h0.z), 0.f);
                v[3] = fmaxf(fmaf(v[3], s0.w, h0.w), 0.f);
                v[4] = fmaxf(fmaf(v[4], s1.x, h1.x), 0.f);
                v[5] = fmaxf(fmaf(v[5], s1.y, h1.y), 0.f);
                v[6] = fmaxf(fmaf(v[6], s1.z, h1.z), 0.f);
                v[7] = fmaxf(fmaf(v[7], s1.w, h1.w), 0.f);
            } else {
                const float* Xf = (const float*)Xp;
                float4 v0 = *(const float4*)&Xf[(size_t)arow * 128 + kc];
                float4 v1 = *(const float4*)&Xf[(size_t)arow * 128 + kc + 4];
                v[0] = v0.x; v[1] = v0.y; v[2] = v0.z; v[3] = v0.w;
                v[4] = v1.x; v[5] = v1.y; v[6] = v1.z; v[7] = v1.w;
            }
        }
        short8v a;
        #pragma unroll
        for (int j = 0; j < 8; ++j) a[j] = (short)bf16_rn(v[j]);
        aF[kb] = a;
    }

    f32x4 acc[8];
    #pragma unroll
    for (int nt = 0; nt < 8; ++nt) {
        acc[nt][0] = 0.f; acc[nt][1] = 0.f; acc[nt][2] = 0.f; acc[nt][3] = 0.f;
    }
    #pragma unroll
    for (int nt = 0; nt < 8; ++nt) {
        #pragma unroll
        for (int kb = 0; kb < 4; ++kb) {
            short8v bF = *(const short8v*)&Wt[(size_t)(nt * 4 + kb) * 512 + L * 8];
            acc[nt] = __builtin_amdgcn_mfma_f32_16x16x32_bf16(aF[kb], bF, acc[nt], 0, 0, 0);
        }
    }

    // epilogue: C row = m0 + hi*4 + reg, col = nt*16 + c16
    #pragma unroll
    for (int reg = 0; reg < 4; ++reg) {
        int row = m0 + hi * 4 + reg;
        if (row < n) {
            float dv = dinv[row];
            #pragma unroll
            for (int nt = 0; nt < 8; ++nt)
                H[(size_t)row * 128 + nt * 16 + c16] = bf16_rn(acc[nt][reg] * dv);
        }
    }
}

// ---------------- pull aggregation + fused BN stats ----------------
// B[d] = bf16( dinv[d] * (H2[d] + sum H2[src]) ); per-block partial sum/sumsq
// of the rounded values accumulated in-register (saves a separate stats pass).
// 32 lanes/node (ushort4 = 4 feats each), 8 nodes/block-iteration, grid-stride.
__global__ __launch_bounds__(256) void k_aggstats(const int* __restrict__ rowptr, const int* __restrict__ csr_src,
                                                  const float* __restrict__ dinv,
                                                  const unsigned short* __restrict__ H2,
                                                  unsigned short* __restrict__ Bo,
                                                  float* __restrict__ partials, int n) {
    __shared__ float sb[8][128];
    int tid = threadIdx.x;
    int sub = tid >> 5, lane = tid & 31;
    const ushort4* Hv = (const ushort4*)H2;              // row = 32 ushort4
    float sA[4] = {0.f, 0.f, 0.f, 0.f}, qA[4] = {0.f, 0.f, 0.f, 0.f};
    for (int node = blockIdx.x * 8 + sub; node < n; node += NAB * 8) {
        int beg = rowptr[node], end = rowptr[node + 1];
        float dv = dinv[node];
        float4 acc = bf4tof(Hv[(size_t)node * 32 + lane]);   // self loop
        float4 acc2 = make_float4(0.f, 0.f, 0.f, 0.f);
        int e = beg;
        for (; e + 1 < end; e += 2) {
            int s0 = csr_src[e], s1 = csr_src[e + 1];
            float4 h0 = bf4tof(Hv[(size_t)s0 * 32 + lane]);
            float4 h1 = bf4tof(Hv[(size_t)s1 * 32 + lane]);
            acc.x += h0.x;  acc.y += h0.y;  acc.z += h0.z;  acc.w += h0.w;
            acc2.x += h1.x; acc2.y += h1.y; acc2.z += h1.z; acc2.w += h1.w;
        }
        if (e < end) {
            int s0 = csr_src[e];
            float4 h0 = bf4tof(Hv[(size_t)s0 * 32 + lane]);
            acc.x += h0.x; acc.y += h0.y; acc.z += h0.z; acc.w += h0.w;
        }
        ushort4 o;
        o.x = bf16_rn((acc.x + acc2.x) * dv);
        o.y = bf16_rn((acc.y + acc2.y) * dv);
        o.z = bf16_rn((acc.z + acc2.z) * dv);
        o.w = bf16_rn((acc.w + acc2.w) * dv);
        *(ushort4*)&Bo[(size_t)node * 128 + lane * 4] = o;
        float v0 = bfs(o.x), v1 = bfs(o.y), v2 = bfs(o.z), v3 = bfs(o.w);
        sA[0] += v0; qA[0] = fmaf(v0, v0, qA[0]);
        sA[1] += v1; qA[1] = fmaf(v1, v1, qA[1]);
        sA[2] += v2; qA[2] = fmaf(v2, v2, qA[2]);
        sA[3] += v3; qA[3] = fmaf(v3, v3, qA[3]);
    }
    #pragma unroll
    for (int j = 0; j < 4; ++j) sb[sub][lane * 4 + j] = sA[j];
    __syncthreads();
    if (tid < 128) partials[(size_t)blockIdx.x * 256 + tid] =
        sb[0][tid] + sb[1][tid] + sb[2][tid] + sb[3][tid] +
        sb[4][tid] + sb[5][tid] + sb[6][tid] + sb[7][tid];
    __syncthreads();
    #pragma unroll
    for (int j = 0; j < 4; ++j) sb[sub][lane * 4 + j] = qA[j];
    __syncthreads();
    if (tid < 128) partials[(size_t)blockIdx.x * 256 + 128 + tid] =
        sb[0][tid] + sb[1][tid] + sb[2][tid] + sb[3][tid] +
        sb[4][tid] + sb[5][tid] + sb[6][tid] + sb[7][tid];
}

// ---------------- finalize stats: one block per feature, parallel over NAB partials ----------------
__global__ __launch_bounds__(256) void k_finstats(const float* __restrict__ partials,
                                                  const float* __restrict__ gamma, const float* __restrict__ beta,
                                                  float* __restrict__ sc, float* __restrict__ sh, int n) {
    __shared__ float red[256];
    int f = blockIdx.x;                       // 0..127
    int t = threadIdx.x;
    int half = t >> 7, idx = t & 127;         // half 0: sum, half 1: sumsq
    float acc = 0.f;
    for (int b = idx; b < NAB; b += 128)
        acc += partials[(size_t)b * 256 + half * 128 + f];
    red[t] = acc;
    __syncthreads();
    #pragma unroll
    for (int off = 64; off; off >>= 1) {
        if (idx < off) red[t] += red[t + off];
        __syncthreads();
    }
    if (t == 0) {
        float s = red[0], q = red[128];
        float invN = 1.0f / (float)n;
        float mu = s * invN;
        float var = fmaf(-mu, mu, q * invN);
        float scale = gamma[f] * rsqrtf(var + EPSV);
        sc[f] = scale;
        sh[f] = fmaf(-mu, scale, beta[f]);
    }
}

// ---------------- fused tail: pool (BN+ReLU on the fly) -> mlp1 -> mlp2 -> mlp3 ----------------
// One block per graph; intermediates live in LDS, no global round-trips.
__global__ __launch_bounds__(256) void k_tail(const unsigned short* __restrict__ X, const int* __restrict__ gptr,
                                              const float* __restrict__ sc, const float* __restrict__ sh,
                                              const float* __restrict__ W1, const float* __restrict__ b1,
                                              const float* __restrict__ W2, const float* __restrict__ b2,
                                              const float* __restrict__ W3, const float* __restrict__ b3,
                                              float* __restrict__ out) {
    __shared__ float grow[256];   // pooled [mean(128) | max(128)]
    __shared__ float shm[256];
    __shared__ float h1s[256];
    __shared__ float wred[2];
    int g = blockIdx.x, t = threadIdx.x;
    int f = t & 127, sub = t >> 7;
    int beg = gptr[g], end = gptr[g + 1];
    float scf = sc[f], shf = sh[f];
    float s = 0.f, m = 0.f;
    for (int r = beg + sub; r < end; r += 2) {
        float v = fmaxf(fmaf(bfs(X[(size_t)r * 128 + f]), scf, shf), 0.f);
        s += v; m = fmaxf(m, v);
    }
    shm[t] = s;
    __syncthreads();
    if (sub == 0) {
        int c = end - beg;
        float inv = (c > 0) ? 1.0f / (float)c : 0.f;
        grow[f] = (s + shm[t + 128]) * inv;
    }
    __syncthreads();
    shm[t] = m;
    __syncthreads();
    if (sub == 1) grow[128 + f] = fmaxf(m, shm[t - 128]);   // 0 for empty graph = reference
    __syncthreads();
    // mlp1: 256 outputs
    float a1 = b1[t];
    #pragma unroll 8
    for (int k = 0; k < 256; ++k) a1 = fmaf(grow[k], W1[k * 256 + t], a1);
    h1s[t] = fmaxf(a1, 0.f);
    __syncthreads();
    // mlp2 (128 outputs, relu) + mlp3 dot-product
    if (t < 128) {
        float a2 = b2[t];
        #pragma unroll 8
        for (int k = 0; k < 256; ++k) a2 = fmaf(h1s[k], W2[k * 128 + t], a2);
        float v = fmaxf(a2, 0.f) * W3[t];
        #pragma unroll
        for (int off = 32; off; off >>= 1) v += __shfl_down(v, off);
        if ((t & 63) == 0) wred[t >> 6] = v;
    }
    __syncthreads();
    if (t == 0) out[g] = wred[0] + wred[1] + b3[0];
}

extern "C" void kernel_launch(void* const* d_in, const int* in_sizes, int n_in,
                              void* d_out, int out_size, void* d_ws, size_t ws_size,
                              hipStream_t stream) {
    const float* x      = (const float*)d_in[0];
    const int*   ei     = (const int*)d_in[1];
    const int*   batch  = (const int*)d_in[2];
    const float* convW0 = (const float*)d_in[3];
    const float* convW  = (const float*)d_in[4];
    // d_in[5] convb: cancels inside BatchNorm, unused
    const float* gamma  = (const float*)d_in[6];
    const float* beta   = (const float*)d_in[7];
    const float* mW1    = (const float*)d_in[8];
    const float* mb1    = (const float*)d_in[9];
    const float* mW2    = (const float*)d_in[10];
    const float* mb2    = (const float*)d_in[11];
    const float* mW3    = (const float*)d_in[12];
    const float* mb3    = (const float*)d_in[13];
    float* out = (float*)d_out;

    const int E = in_sizes[1] / 2;
    const int n = in_sizes[0] / FH;
    const int npad = (n + 4) & ~3;
    const int nb = (n + 1023) / 1024;
    const int nbk = (n + 63) >> 6;            // 64-node buckets

    // workspace layout (16B-aligned chunks)
    float*          A     = (float*)d_ws;                     // n*128 f32 slot: bf16 H2; tmp overlays pre-loop
    unsigned short* H2b   = (unsigned short*)A;
    unsigned*       tmp   = (unsigned*)A;                     // E packed words (3.2MB), pre-loop only
    float*    B       = A + (size_t)n * FH;                   // n*128 f32 slot: bf16 B; bcur overlays pre-loop
    unsigned short* Bb = (unsigned short*)B;
    int*      bcur    = (int*)B;                              // nbk*CPAD ints (50KB), pre-loop only
    float*    dinv    = B + (size_t)n * FH;                   // n
    unsigned* deg     = (unsigned*)(dinv + n);                // n
    float*    parts   = (float*)(deg + n);                    // NAB*256 (2MB)
    float*    sc      = parts + (size_t)NAB * 256;            // 128
    float*    sh      = sc + 128;                             // 128
    int*      gptr    = (int*)(sh + 128);                     // G+1 (pad 4)
    int*      rowptr  = gptr + ((GG + 4) & ~3);               // n+1 (padded)
    int*      bsum    = rowptr + npad;                        // 64
    int*      csrsrc  = bsum + 64;                            // E
    unsigned short* Wt = (unsigned short*)(csrsrc + ((E + 3) & ~3));  // 3*16384 ushorts

    const int* srcI = ei;
    const int* dstI = ei + E;

    const int degB  = (E + 255) / 256;
    const int gptrB = (GG + 1 + 255) / 256;
    const int wprepB = 3 * 16384 / 256;

    // ---- CSR build (dense writes, low-contention atomics) + setup ----
    hipMemsetAsync(deg, 0, (size_t)n * sizeof(unsigned), stream);
    k_setup<<<degB + gptrB + wprepB, 256, 0, stream>>>(dstI, deg, E, batch, gptr, n,
                                                       convW0, convW, Wt, degB, gptrB);
    k_scan1<<<nb, 1024, 0, stream>>>(deg, rowptr, bsum, dinv, n);
    k_scan3<<<nb, 1024, 0, stream>>>(rowptr, bsum, deg, bcur, n);
    k_binscatter<<<(E + EPB - 1) / EPB, 256, 0, stream>>>(srcI, dstI, bcur, tmp, E, nbk);
    k_finesort<<<nbk, 256, 0, stream>>>(tmp, rowptr, csrsrc, n);

    for (int l = 0; l < 3; ++l) {
        if (l == 0)
            k_gemm<false><<<(n + 63) / 64, 256, 0, stream>>>(x, Wt, dinv, nullptr, nullptr, H2b, n);
        else
            k_gemm<true><<<(n + 63) / 64, 256, 0, stream>>>(Bb, Wt + (size_t)l * 16384, dinv, sc, sh, H2b, n);
        k_aggstats<<<NAB, 256, 0, stream>>>(rowptr, csrsrc, dinv, H2b, Bb, parts, n);
        k_finstats<<<FH, 256, 0, stream>>>(parts, gamma + l * FH, beta + l * FH, sc, sh, n);
    }

    // fused tail: pool (applies layer-3 BN+ReLU) -> 3-layer MLP, one dispatch
    k_tail<<<GG, 256, 0, stream>>>(Bb, gptr, sc, sh, mW1, mb1, mW2, mb2, mW3, mb3, out);
}